// Round 16
// baseline (1339.212 us; speedup 1.0000x reference)
//
#include <hip/hip_runtime.h>

#define NROWS 32768
#define DDIM  512
#define KCENT 8192

// out layout (floats): qout[16777216] loss[16777216] idx[32768] cbv[4194304] counts[8192]
#define O_LOSS 16777216
#define O_IDX  33554432
#define O_CBV  33587200
#define O_CNT  37781504
#define O_PBLK 8388608      // float offset of pblk inside qout region (32 MB in)

typedef float f32x4 __attribute__((ext_vector_type(4)));
typedef _Float16 f16x8 __attribute__((ext_vector_type(8)));

// ---- kernel 0: fp32 -> f16, 8-slot XOR pre-swizzle within each 128B K-chunk ----
// stored slot u of (row r, chunk dk) holds logical unit dk*8 + (u ^ (r&7))
__global__ __launch_bounds__(256) void vq_cvt_swz8(
    const float* __restrict__ src, char* __restrict__ dst)
{
    const int gid = blockIdx.x * 256 + threadIdx.x;   // one 16B f16 unit (8 floats)
    const int r = gid >> 6, w = gid & 63, dk = w >> 3, u = w & 7;
    const float4* p = (const float4*)(src + (size_t)r * DDIM + (dk*8 + (u ^ (r & 7))) * 8);
    float4 a = p[0], b = p[1];
    f16x8 h;
    h[0]=(_Float16)a.x; h[1]=(_Float16)a.y; h[2]=(_Float16)a.z; h[3]=(_Float16)a.w;
    h[4]=(_Float16)b.x; h[5]=(_Float16)b.y; h[6]=(_Float16)b.z; h[7]=(_Float16)b.w;
    *(f16x8*)(dst + (size_t)gid * 16) = h;
}

// ---- kernel 1: centroid squared norms (fp64 accumulate) + counts=1 ----
__global__ __launch_bounds__(256) void vq_cnorm_kernel(
    const float* __restrict__ CB, float* __restrict__ cnorm, float* __restrict__ counts)
{
    const int wid  = threadIdx.x >> 6;
    const int lane = threadIdx.x & 63;
    const int cid  = blockIdx.x * 4 + wid;
    const float4* p = (const float4*)(CB + (size_t)cid * DDIM + lane * 8);
    float4 a = p[0], b = p[1];
    double s = (double)a.x*a.x + (double)a.y*a.y + (double)a.z*a.z + (double)a.w*a.w
             + (double)b.x*b.x + (double)b.y*b.y + (double)b.z*b.z + (double)b.w*b.w;
    #pragma unroll
    for (int off = 32; off > 0; off >>= 1) s += __shfl_down(s, off);
    if (lane == 0) { cnorm[cid] = (float)s; counts[cid] = 1.0f; }
}

__device__ __forceinline__ void t2_update(float s, int c,
                                          float& v1, int& i1, float& v2, int& i2)
{
    if (s < v1)      { v2 = v1; i2 = i1; v1 = s; i1 = c; }
    else if (s < v2) { v2 = s;  i2 = c; }
}

__device__ __forceinline__ void t2_merge(float b1, int bi1, float b2, int bi2,
                                         float& a1, int& ai1, float& a2, int& ai2)
{
    if (b1 < a1 || (b1 == a1 && bi1 < ai1)) {
        float o1 = a1; int oi1 = ai1;
        a1 = b1; ai1 = bi1;
        if (b2 < o1 || (b2 == o1 && bi2 < oi1)) { a2 = b2; ai2 = bi2; }
        else                                    { a2 = o1; ai2 = oi1; }
    } else {
        if (b1 < a2 || (b1 == a2 && bi1 < ai2)) { a2 = b1; ai2 = bi1; }
    }
}

__device__ __forceinline__ void gl16(const char* g, const char* l)
{
    __builtin_amdgcn_global_load_lds(
        (const __attribute__((address_space(1))) void*)g,
        (__attribute__((address_space(3))) void*)l, 16, 0, 0);
}

// ---- kernel 2: long-pipeline sweep GEMM: 64 rows x ALL 8192 cols per block ----
// 512 thr = 8 waves, each a 64x64 tile (m4 x n4 @ 16x16x32 f16, acc=64 regs).
// A (64x512 f16 = 64KB) LDS-resident, staged once. B 32KB/phase double-buffered.
// 256 phases (16 sweeps x 16 ksteps), counted vmcnt(4) + raw barriers (T4).
// Per-sweep epilogue: reg top-2 + 16-lane butterfly, then CROSS-WAVE merge via
// buf1 scratch (dead between k=15 compute and next k=0 restage) -> global pblk.
__global__ __launch_bounds__(512, 2) void vq_sweep_kernel(
    const char* __restrict__ Xf, const char* __restrict__ Cf,
    const float* __restrict__ cnorm, float4* __restrict__ pblk)
{
    __shared__ __align__(16) char lds[131072];  // A 64KB | B0 32KB | B1 32KB

    const int blk  = blockIdx.x;       // rows blk*64 .. +64
    const int t    = threadIdx.x;
    const int lane = t & 63;
    const int cg   = t >> 6;           // 8 col-groups of 64
    const int l15  = lane & 15;
    const int lg   = lane >> 4;        // 0..3

    // ---- prologue: stage A (4096 units, linear copy of swz8 layout) ----
    #pragma unroll
    for (int i = 0; i < 8; ++i) {
        const int d = i*512 + t;
        gl16(Xf + (size_t)(blk*64 + (d >> 6))*1024 + (d & 63)*16, &lds[d*16]);
    }

    // B stage for (sweep S, kstep K) into buf: dst [c 0..511][p 0..3] 16B units;
    // position p holds logical unit p ^ ((c>>1)&3) of the 4-unit kstep group.
    #define STAGE_B(S, K, BUF) {                                              \
        _Pragma("unroll")                                                     \
        for (int i = 0; i < 4; ++i) {                                         \
            const int d  = i*512 + t;                                         \
            const int c  = d >> 2;                                            \
            const int li = (d & 3) ^ ((c >> 1) & 3);                          \
            const int sub = ((K) & 1)*4 + li;                                 \
            gl16(Cf + (size_t)((S)*512 + c)*1024 + ((K) >> 1)*128             \
                    + ((sub ^ (c & 7)) * 16),                                 \
                 &lds[65536 + (BUF)*32768 + d*16]);                           \
        } }

    STAGE_B(0, 0, 0);
    __syncthreads();     // drain A + B(0,0); only full drain in the kernel

    f32x4 acc[4][4];
    #pragma unroll
    for (int m = 0; m < 4; ++m)
        #pragma unroll
        for (int n = 0; n < 4; ++n) {
            f32x4 z = {0.f, 0.f, 0.f, 0.f};
            acc[m][n] = z;
        }

    for (int s = 0; s < 16; ++s) {
        #pragma unroll
        for (int k = 0; k < 16; ++k) {           // fully unrolled: k static
            // stage next phase; never drain to 0 except at the very end
            if (k < 15) {
                STAGE_B(s, k + 1, (k + 1) & 1);
                asm volatile("s_waitcnt vmcnt(4)\n\ts_barrier" ::: "memory");
            } else if (s < 15) {
                STAGE_B(s + 1, 0, 0);
                asm volatile("s_waitcnt vmcnt(4)\n\ts_barrier" ::: "memory");
            } else {
                asm volatile("s_waitcnt vmcnt(0)\n\ts_barrier" ::: "memory");
            }
            const char* bb = &lds[65536 + (k & 1)*32768];
            const int kb  = (k >> 1)*128;
            const int sA  = (k & 1)*4 + lg;      // static per unrolled k
            f16x8 A[4], B[4];
            #pragma unroll
            for (int m = 0; m < 4; ++m) {
                const int r = m*16 + l15;
                A[m] = *(const f16x8*)(&lds[r*1024 + kb + ((sA ^ (r & 7)) * 16)]);
            }
            #pragma unroll
            for (int n = 0; n < 4; ++n) {
                const int c = cg*64 + n*16 + l15;
                B[n] = *(const f16x8*)(bb + c*64 + ((lg ^ ((c >> 1) & 3)) * 16));
            }
            #pragma unroll
            for (int m = 0; m < 4; ++m)
                #pragma unroll
                for (int n = 0; n < 4; ++n)
                    acc[m][n] = __builtin_amdgcn_mfma_f32_16x16x32_f16(A[m], B[n], acc[m][n], 0, 0, 0);
            asm volatile("s_barrier" ::: "memory");   // reads done before restage
        }

        // ---- per-sweep epilogue ----
        // buf1 (lds[98304..]) is dead: k=15 computed from it, and it is only
        // restaged at next sweep's k=0 (issued after the final barrier below).
        float4* red = (float4*)&lds[98304];   // [64 rows][8 cg]
        const int colb = s*512 + cg*64;
        {
            float cn[4];
            #pragma unroll
            for (int n = 0; n < 4; ++n) cn[n] = cnorm[colb + n*16 + l15];
            #pragma unroll
            for (int m = 0; m < 4; ++m) {
                #pragma unroll
                for (int j = 0; j < 4; ++j) {
                    float v1 = 3.4e38f, v2 = 3.4e38f;
                    int   i1 = 0x7fffffff, i2 = 0x7fffffff;
                    #pragma unroll
                    for (int n = 0; n < 4; ++n)
                        t2_update(fmaf(-2.0f, acc[m][n][j], cn[n]),
                                  colb + n*16 + l15, v1, i1, v2, i2);
                    #pragma unroll
                    for (int off = 1; off <= 8; off <<= 1) {
                        float e1 = __shfl_xor(v1, off), e2 = __shfl_xor(v2, off);
                        int  f1 = __shfl_xor(i1, off),  f2 = __shfl_xor(i2, off);
                        t2_merge(e1, f1, e2, f2, v1, i1, v2, i2);
                    }
                    if (l15 == 0) {
                        float4 w; w.x = v1; w.y = __int_as_float(i1);
                        w.z = v2; w.w = __int_as_float(i2);
                        red[(m*16 + lg*4 + j)*8 + cg] = w;
                    }
                }
                #pragma unroll
                for (int n = 0; n < 4; ++n) {
                    f32x4 z = {0.f, 0.f, 0.f, 0.f};
                    acc[m][n] = z;
                }
            }
        }
        // all scratch writes visible to all waves
        asm volatile("s_waitcnt lgkmcnt(0)\n\ts_barrier" ::: "memory");
        if (t < 64) {
            float4 e0 = red[t*8 + 0];
            float v1 = e0.x, v2 = e0.z;
            int   i1 = __float_as_int(e0.y), i2 = __float_as_int(e0.w);
            #pragma unroll
            for (int w8 = 1; w8 < 8; ++w8) {
                float4 e = red[t*8 + w8];
                t2_merge(e.x, __float_as_int(e.y), e.z, __float_as_int(e.w),
                         v1, i1, v2, i2);
            }
            float4 w; w.x = v1; w.y = __int_as_float(i1);
            w.z = v2; w.w = __int_as_float(i2);
            pblk[(size_t)(blk*64 + t)*16 + s] = w;
        }
        // merge reads done before anyone restages buf1 at next sweep's k=0
        asm volatile("s_waitcnt lgkmcnt(0)\n\ts_barrier" ::: "memory");
    }
    #undef STAGE_B
}

// ---- kernel 3: fold the 16 per-sweep top-2 entries per row -> global top-2 ----
__global__ __launch_bounds__(256) void vq_merge16(
    const float4* __restrict__ pblk, int* __restrict__ pmini2)
{
    const int row = blockIdx.x * 256 + threadIdx.x;
    const float4* e = pblk + (size_t)row * 16;
    float4 e0 = e[0];
    float v1 = e0.x, v2 = e0.z;
    int   i1 = __float_as_int(e0.y), i2 = __float_as_int(e0.w);
    #pragma unroll
    for (int s = 1; s < 16; ++s) {
        float4 es = e[s];
        t2_merge(es.x, __float_as_int(es.y), es.z, __float_as_int(es.w),
                 v1, i1, v2, i2);
    }
    pmini2[row*2 + 0] = i1;
    pmini2[row*2 + 1] = i2;
}

// ---- kernel 4: exact fp64 resolve of the 2 candidates + write all outputs ----
__global__ __launch_bounds__(256) void vq_resolve_out(
    const float* __restrict__ X, const float* __restrict__ CB,
    const int* __restrict__ pmini2, float* __restrict__ out)
{
    const int wid  = threadIdx.x >> 6;
    const int lane = threadIdx.x & 63;
    const int row  = blockIdx.x * 4 + wid;
    const int i0 = pmini2[row*2 + 0], i1 = pmini2[row*2 + 1];

    const float4* xp = (const float4*)(X + (size_t)row * DDIM + lane * 8);
    float4 xa = xp[0], xb = xp[1];
    const float4* p0 = (const float4*)(CB + (size_t)i0 * DDIM + lane * 8);
    float4 c0a = p0[0], c0b = p0[1];
    const float4* p1 = (const float4*)(CB + (size_t)i1 * DDIM + lane * 8);
    float4 c1a = p1[0], c1b = p1[1];

    double d0 = 0.0, d1 = 0.0, e;
    e = (double)xa.x - c0a.x; d0 += e*e;  e = (double)xa.y - c0a.y; d0 += e*e;
    e = (double)xa.z - c0a.z; d0 += e*e;  e = (double)xa.w - c0a.w; d0 += e*e;
    e = (double)xb.x - c0b.x; d0 += e*e;  e = (double)xb.y - c0b.y; d0 += e*e;
    e = (double)xb.z - c0b.z; d0 += e*e;  e = (double)xb.w - c0b.w; d0 += e*e;
    e = (double)xa.x - c1a.x; d1 += e*e;  e = (double)xa.y - c1a.y; d1 += e*e;
    e = (double)xa.z - c1a.z; d1 += e*e;  e = (double)xa.w - c1a.w; d1 += e*e;
    e = (double)xb.x - c1b.x; d1 += e*e;  e = (double)xb.y - c1b.y; d1 += e*e;
    e = (double)xb.z - c1b.z; d1 += e*e;  e = (double)xb.w - c1b.w; d1 += e*e;
    #pragma unroll
    for (int off = 1; off < 64; off <<= 1) {
        d0 += __shfl_xor(d0, off);
        d1 += __shfl_xor(d1, off);
    }

    const bool w1 = (d1 < d0) || (d1 == d0 && i1 < i0);
    const int idxw = w1 ? i1 : i0;
    float4 qa, qb;
    qa.x = w1 ? c1a.x : c0a.x;  qa.y = w1 ? c1a.y : c0a.y;
    qa.z = w1 ? c1a.z : c0a.z;  qa.w = w1 ? c1a.w : c0a.w;
    qb.x = w1 ? c1b.x : c0b.x;  qb.y = w1 ? c1b.y : c0b.y;
    qb.z = w1 ? c1b.z : c0b.z;  qb.w = w1 ? c1b.w : c0b.w;

    float4 qoa, loa, qob, lob;
    float d, s;
    d = qa.x - xa.x; qoa.x = xa.x + d; s = d*d; loa.x = s + 0.25f*s;
    d = qa.y - xa.y; qoa.y = xa.y + d; s = d*d; loa.y = s + 0.25f*s;
    d = qa.z - xa.z; qoa.z = xa.z + d; s = d*d; loa.z = s + 0.25f*s;
    d = qa.w - xa.w; qoa.w = xa.w + d; s = d*d; loa.w = s + 0.25f*s;
    d = qb.x - xb.x; qob.x = xb.x + d; s = d*d; lob.x = s + 0.25f*s;
    d = qb.y - xb.y; qob.y = xb.y + d; s = d*d; lob.y = s + 0.25f*s;
    d = qb.z - xb.z; qob.z = xb.z + d; s = d*d; lob.z = s + 0.25f*s;
    d = qb.w - xb.w; qob.w = xb.w + d; s = d*d; lob.w = s + 0.25f*s;

    ((float4*)out)[(size_t)row*128 + lane*2 + 0] = qoa;
    ((float4*)out)[(size_t)row*128 + lane*2 + 1] = qob;
    ((float4*)(out + O_LOSS))[(size_t)row*128 + lane*2 + 0] = loa;
    ((float4*)(out + O_LOSS))[(size_t)row*128 + lane*2 + 1] = lob;
    if (lane == 0) out[O_IDX + row] = (float)idxw;
}

extern "C" void kernel_launch(void* const* d_in, const int* in_sizes, int n_in,
                              void* d_out, int out_size, void* d_ws, size_t ws_size,
                              hipStream_t stream)
{
    const float* X  = (const float*)d_in[0];
    const float* CB = (const float*)d_in[1];
    float* out = (float*)d_out;

    // big scratch parked in out regions (all rewritten by the final kernels)
    char*   XsB  = (char*)out;                    // 32 MB f16 X       (qout front half)
    float4* pblk = (float4*)(out + O_PBLK);       //  8 MB top-2/sweep (qout back half)
    char*   CBsB = (char*)(out + O_LOSS);         //  8 MB f16 CB      (loss region)

    float* cnorm  = (float*)d_ws;                 // 8192 floats
    int*   pmini2 = (int*)(cnorm + KCENT);        // 2*32768 ints

    vq_cvt_swz8<<<(NROWS*64)/256, 256, 0, stream>>>(X, XsB);
    vq_cvt_swz8<<<(KCENT*64)/256, 256, 0, stream>>>(CB, CBsB);
    vq_cnorm_kernel<<<KCENT/4, 256, 0, stream>>>(CB, cnorm, out + O_CNT);
    vq_sweep_kernel<<<NROWS/64, 512, 0, stream>>>(XsB, CBsB, cnorm, pblk);
    vq_merge16<<<NROWS/256, 256, 0, stream>>>(pblk, pmini2);
    vq_resolve_out<<<NROWS/4, 256, 0, stream>>>(X, CB, pmini2, out);
    hipMemcpyAsync(out + O_CBV, CB, (size_t)KCENT * DDIM * sizeof(float),
                   hipMemcpyDeviceToDevice, stream);
}

// Round 17
// 964.885 us; speedup vs baseline: 1.3880x; 1.3880x over previous
//
#include <hip/hip_runtime.h>

#define NROWS 32768
#define DDIM  512
#define KCENT 8192

// out layout (floats): qout[16777216] loss[16777216] idx[32768] cbv[4194304] counts[8192]
#define O_LOSS 16777216
#define O_IDX  33554432
#define O_CBV  33587200
#define O_CNT  37781504
#define O_PBLK 8388608      // float offset of pblk inside qout region (32 MB in)

typedef float f32x4 __attribute__((ext_vector_type(4)));
typedef _Float16 f16x8 __attribute__((ext_vector_type(8)));

// ---- kernel 0: fp32 -> f16, 8-slot XOR pre-swizzle within each 128B K-chunk ----
// stored slot u of (row r, chunk dk) holds logical unit dk*8 + (u ^ (r&7))
__global__ __launch_bounds__(256) void vq_cvt_swz8(
    const float* __restrict__ src, char* __restrict__ dst)
{
    const int gid = blockIdx.x * 256 + threadIdx.x;   // one 16B f16 unit (8 floats)
    const int r = gid >> 6, w = gid & 63, dk = w >> 3, u = w & 7;
    const float4* p = (const float4*)(src + (size_t)r * DDIM + (dk*8 + (u ^ (r & 7))) * 8);
    float4 a = p[0], b = p[1];
    f16x8 h;
    h[0]=(_Float16)a.x; h[1]=(_Float16)a.y; h[2]=(_Float16)a.z; h[3]=(_Float16)a.w;
    h[4]=(_Float16)b.x; h[5]=(_Float16)b.y; h[6]=(_Float16)b.z; h[7]=(_Float16)b.w;
    *(f16x8*)(dst + (size_t)gid * 16) = h;
}

// ---- kernel 1: centroid squared norms (fp64 accumulate) + counts=1 ----
__global__ __launch_bounds__(256) void vq_cnorm_kernel(
    const float* __restrict__ CB, float* __restrict__ cnorm, float* __restrict__ counts)
{
    const int wid  = threadIdx.x >> 6;
    const int lane = threadIdx.x & 63;
    const int cid  = blockIdx.x * 4 + wid;
    const float4* p = (const float4*)(CB + (size_t)cid * DDIM + lane * 8);
    float4 a = p[0], b = p[1];
    double s = (double)a.x*a.x + (double)a.y*a.y + (double)a.z*a.z + (double)a.w*a.w
             + (double)b.x*b.x + (double)b.y*b.y + (double)b.z*b.z + (double)b.w*b.w;
    #pragma unroll
    for (int off = 32; off > 0; off >>= 1) s += __shfl_down(s, off);
    if (lane == 0) { cnorm[cid] = (float)s; counts[cid] = 1.0f; }
}

__device__ __forceinline__ void t2_update(float s, int c,
                                          float& v1, int& i1, float& v2, int& i2)
{
    if (s < v1)      { v2 = v1; i2 = i1; v1 = s; i1 = c; }
    else if (s < v2) { v2 = s;  i2 = c; }
}

__device__ __forceinline__ void t2_merge(float b1, int bi1, float b2, int bi2,
                                         float& a1, int& ai1, float& a2, int& ai2)
{
    if (b1 < a1 || (b1 == a1 && bi1 < ai1)) {
        float o1 = a1; int oi1 = ai1;
        a1 = b1; ai1 = bi1;
        if (b2 < o1 || (b2 == o1 && bi2 < oi1)) { a2 = b2; ai2 = bi2; }
        else                                    { a2 = o1; ai2 = oi1; }
    } else {
        if (b1 < a2 || (b1 == a2 && bi1 < ai2)) { a2 = b1; ai2 = bi1; }
    }
}

__device__ __forceinline__ void gl16(const char* g, const char* l)
{
    __builtin_amdgcn_global_load_lds(
        (const __attribute__((address_space(1))) void*)g,
        (__attribute__((address_space(3))) void*)l, 16, 0, 0);
}

// ---- kernel 2: 256x256 f16 GEMM tile (HALVED staging traffic: 2 GB total) ----
// 1024 thr = 16 waves (4 wr x 4 wc), each a 64x64 tile (m4 x n4, acc=64 regs).
// BK=64, double-buffered (2 x 64KB LDS), counted vmcnt(4) + raw barriers.
// XCD mapping: each XCD owns 4 col-blocks (1 MB B slice, L2-resident).
// Epilogue: per-wave reg top-2 + butterfly, cross-wave merge via LDS -> pblk.
__global__ __launch_bounds__(1024, 4) void vq_gemm_kernel(
    const char* __restrict__ Xf, const char* __restrict__ Cf,
    const float* __restrict__ cnorm, float4* __restrict__ pblk)
{
    __shared__ __align__(16) char lds[131072];   // buf{0,1}: A 32KB | B 32KB

    const int bid = blockIdx.x;
    const int xcd = bid & 7;
    const int idx = bid >> 3;            // 0..511
    const int cb  = xcd * 4 + (idx & 3); // 0..31  (col-block of 256)
    const int rb  = idx >> 2;            // 0..127 (row-block of 256)

    const int t    = threadIdx.x;        // 0..1023
    const int lane = t & 63;
    const int wid  = t >> 6;             // 0..15
    const int wr   = wid >> 2;           // 4 row-groups of 64
    const int wc   = wid & 3;            // 4 col-groups of 64
    const int l15  = lane & 15;
    const int lg   = lane >> 4;

    // staging: per phase 2048 A units + 2048 B units; thread covers g = t, t+1024
    // ((t+1024)>>3 = (t>>3)+128, (t+1024)&7 = t&7  ->  +128 rows = +128*1024 B)
    const size_t a0 = (size_t)(rb*256 + (t >> 3))*1024 + (t & 7)*16;
    const size_t b0 = (size_t)(cb*256 + (t >> 3))*1024 + (t & 7)*16;

    #define STAGE(dk, buf) {                                             \
        gl16(Xf + a0          + (dk)*128, &lds[(buf)*65536 +         t*16]); \
        gl16(Xf + a0 + 131072 + (dk)*128, &lds[(buf)*65536 + 16384 + t*16]); \
        gl16(Cf + b0          + (dk)*128, &lds[(buf)*65536 + 32768 + t*16]); \
        gl16(Cf + b0 + 131072 + (dk)*128, &lds[(buf)*65536 + 49152 + t*16]); }

    f32x4 acc[4][4];
    #pragma unroll
    for (int m = 0; m < 4; ++m)
        #pragma unroll
        for (int n = 0; n < 4; ++n) {
            f32x4 z = {0.f, 0.f, 0.f, 0.f};
            acc[m][n] = z;
        }

    STAGE(0, 0);
    __syncthreads();    // full drain once (prologue)

    for (int dk = 0; dk < 8; ++dk) {
        if (dk < 7) {
            STAGE(dk + 1, (dk + 1) & 1);
            // wait current buffer's 4 loads (issued one phase ago); keep 4 in flight
            asm volatile("s_waitcnt vmcnt(4)\n\ts_barrier" ::: "memory");
        } else {
            asm volatile("s_waitcnt vmcnt(0)\n\ts_barrier" ::: "memory");
        }
        const char* bb = &lds[(dk & 1)*65536];
        #pragma unroll
        for (int ks = 0; ks < 2; ++ks) {
            const int ku = ks*4 + lg;
            f16x8 A[4], B[4];
            #pragma unroll
            for (int m = 0; m < 4; ++m) {
                const int r = wr*64 + m*16 + l15;
                A[m] = *(const f16x8*)(bb + r*128 + ((ku ^ (r & 7)) * 16));
            }
            #pragma unroll
            for (int n = 0; n < 4; ++n) {
                const int r = wc*64 + n*16 + l15;
                B[n] = *(const f16x8*)(bb + 32768 + r*128 + ((ku ^ (r & 7)) * 16));
            }
            #pragma unroll
            for (int m = 0; m < 4; ++m)
                #pragma unroll
                for (int n = 0; n < 4; ++n)
                    acc[m][n] = __builtin_amdgcn_mfma_f32_16x16x32_f16(A[m], B[n], acc[m][n], 0, 0, 0);
        }
        asm volatile("s_barrier" ::: "memory");   // reads done before restage
    }
    #undef STAGE

    // ---- epilogue: per-wave top-2 over its 64 cols, butterfly, cross-wave merge ----
    const int colbase = cb*256 + wc*64;
    float cn[4];
    int   cl[4];
    #pragma unroll
    for (int n = 0; n < 4; ++n) {
        cl[n] = colbase + n*16 + l15;
        cn[n] = cnorm[cl[n]];
    }
    float4* redq = (float4*)&lds[0];    // [256 rows][4 wc] = 16 KB (buf0 A, dead)

    #pragma unroll
    for (int m = 0; m < 4; ++m)
        #pragma unroll
        for (int j = 0; j < 4; ++j) {
            float v1 = 3.4e38f, v2 = 3.4e38f;
            int   i1 = 0x7fffffff, i2 = 0x7fffffff;
            #pragma unroll
            for (int n = 0; n < 4; ++n)
                t2_update(fmaf(-2.0f, acc[m][n][j], cn[n]), cl[n], v1, i1, v2, i2);
            #pragma unroll
            for (int off = 1; off <= 8; off <<= 1) {
                float e1 = __shfl_xor(v1, off), e2 = __shfl_xor(v2, off);
                int  f1 = __shfl_xor(i1, off),  f2 = __shfl_xor(i2, off);
                t2_merge(e1, f1, e2, f2, v1, i1, v2, i2);
            }
            if (l15 == 0) {
                float4 w; w.x = v1; w.y = __int_as_float(i1);
                w.z = v2; w.w = __int_as_float(i2);
                redq[(wr*64 + m*16 + lg*4 + j)*4 + wc] = w;
            }
        }

    __syncthreads();
    if (t < 256) {
        float4 e0 = redq[t*4 + 0], e1 = redq[t*4 + 1];
        float4 e2 = redq[t*4 + 2], e3 = redq[t*4 + 3];
        float v1 = e0.x, v2 = e0.z;
        int   i1 = __float_as_int(e0.y), i2 = __float_as_int(e0.w);
        t2_merge(e1.x, __float_as_int(e1.y), e1.z, __float_as_int(e1.w), v1, i1, v2, i2);
        t2_merge(e2.x, __float_as_int(e2.y), e2.z, __float_as_int(e2.w), v1, i1, v2, i2);
        t2_merge(e3.x, __float_as_int(e3.y), e3.z, __float_as_int(e3.w), v1, i1, v2, i2);
        float4 w; w.x = v1; w.y = __int_as_float(i1); w.z = v2; w.w = __int_as_float(i2);
        pblk[((size_t)(rb*256 + t))*32 + cb] = w;
    }
}

// ---- kernel 3: merge 32 col-block top-2's per row -> global top-2 ----
__global__ __launch_bounds__(256) void vq_merge32(
    const float4* __restrict__ pblk, int* __restrict__ pmini2)
{
    const int row = blockIdx.x * 256 + threadIdx.x;
    const float4* e = pblk + (size_t)row * 32;
    float4 e0 = e[0];
    float v1 = e0.x, v2 = e0.z;
    int   i1 = __float_as_int(e0.y), i2 = __float_as_int(e0.w);
    #pragma unroll
    for (int s = 1; s < 32; ++s) {
        float4 es = e[s];
        t2_merge(es.x, __float_as_int(es.y), es.z, __float_as_int(es.w),
                 v1, i1, v2, i2);
    }
    pmini2[row*2 + 0] = i1;
    pmini2[row*2 + 1] = i2;
}

// ---- kernel 4: exact fp64 resolve of the 2 candidates + write all outputs ----
__global__ __launch_bounds__(256) void vq_resolve_out(
    const float* __restrict__ X, const float* __restrict__ CB,
    const int* __restrict__ pmini2, float* __restrict__ out)
{
    const int wid  = threadIdx.x >> 6;
    const int lane = threadIdx.x & 63;
    const int row  = blockIdx.x * 4 + wid;
    const int i0 = pmini2[row*2 + 0], i1 = pmini2[row*2 + 1];

    const float4* xp = (const float4*)(X + (size_t)row * DDIM + lane * 8);
    float4 xa = xp[0], xb = xp[1];
    const float4* p0 = (const float4*)(CB + (size_t)i0 * DDIM + lane * 8);
    float4 c0a = p0[0], c0b = p0[1];
    const float4* p1 = (const float4*)(CB + (size_t)i1 * DDIM + lane * 8);
    float4 c1a = p1[0], c1b = p1[1];

    double d0 = 0.0, d1 = 0.0, e;
    e = (double)xa.x - c0a.x; d0 += e*e;  e = (double)xa.y - c0a.y; d0 += e*e;
    e = (double)xa.z - c0a.z; d0 += e*e;  e = (double)xa.w - c0a.w; d0 += e*e;
    e = (double)xb.x - c0b.x; d0 += e*e;  e = (double)xb.y - c0b.y; d0 += e*e;
    e = (double)xb.z - c0b.z; d0 += e*e;  e = (double)xb.w - c0b.w; d0 += e*e;
    e = (double)xa.x - c1a.x; d1 += e*e;  e = (double)xa.y - c1a.y; d1 += e*e;
    e = (double)xa.z - c1a.z; d1 += e*e;  e = (double)xa.w - c1a.w; d1 += e*e;
    e = (double)xb.x - c1b.x; d1 += e*e;  e = (double)xb.y - c1b.y; d1 += e*e;
    e = (double)xb.z - c1b.z; d1 += e*e;  e = (double)xb.w - c1b.w; d1 += e*e;
    #pragma unroll
    for (int off = 1; off < 64; off <<= 1) {
        d0 += __shfl_xor(d0, off);
        d1 += __shfl_xor(d1, off);
    }

    const bool w1 = (d1 < d0) || (d1 == d0 && i1 < i0);
    const int idxw = w1 ? i1 : i0;
    float4 qa, qb;
    qa.x = w1 ? c1a.x : c0a.x;  qa.y = w1 ? c1a.y : c0a.y;
    qa.z = w1 ? c1a.z : c0a.z;  qa.w = w1 ? c1a.w : c0a.w;
    qb.x = w1 ? c1b.x : c0b.x;  qb.y = w1 ? c1b.y : c0b.y;
    qb.z = w1 ? c1b.z : c0b.z;  qb.w = w1 ? c1b.w : c0b.w;

    float4 qoa, loa, qob, lob;
    float d, s;
    d = qa.x - xa.x; qoa.x = xa.x + d; s = d*d; loa.x = s + 0.25f*s;
    d = qa.y - xa.y; qoa.y = xa.y + d; s = d*d; loa.y = s + 0.25f*s;
    d = qa.z - xa.z; qoa.z = xa.z + d; s = d*d; loa.z = s + 0.25f*s;
    d = qa.w - xa.w; qoa.w = xa.w + d; s = d*d; loa.w = s + 0.25f*s;
    d = qb.x - xb.x; qob.x = xb.x + d; s = d*d; lob.x = s + 0.25f*s;
    d = qb.y - xb.y; qob.y = xb.y + d; s = d*d; lob.y = s + 0.25f*s;
    d = qb.z - xb.z; qob.z = xb.z + d; s = d*d; lob.z = s + 0.25f*s;
    d = qb.w - xb.w; qob.w = xb.w + d; s = d*d; lob.w = s + 0.25f*s;

    ((float4*)out)[(size_t)row*128 + lane*2 + 0] = qoa;
    ((float4*)out)[(size_t)row*128 + lane*2 + 1] = qob;
    ((float4*)(out + O_LOSS))[(size_t)row*128 + lane*2 + 0] = loa;
    ((float4*)(out + O_LOSS))[(size_t)row*128 + lane*2 + 1] = lob;
    if (lane == 0) out[O_IDX + row] = (float)idxw;
}

extern "C" void kernel_launch(void* const* d_in, const int* in_sizes, int n_in,
                              void* d_out, int out_size, void* d_ws, size_t ws_size,
                              hipStream_t stream)
{
    const float* X  = (const float*)d_in[0];
    const float* CB = (const float*)d_in[1];
    float* out = (float*)d_out;

    // big scratch parked in out regions (all rewritten by the final kernels)
    char*   XsB  = (char*)out;                    // 32 MB f16 X      (qout front half)
    float4* pblk = (float4*)(out + O_PBLK);       // 16 MB top-2/blk  (qout back half)
    char*   CBsB = (char*)(out + O_LOSS);         //  8 MB f16 CB     (loss region)

    float* cnorm  = (float*)d_ws;                 // 8192 floats
    int*   pmini2 = (int*)(cnorm + KCENT);        // 2*32768 ints

    vq_cvt_swz8<<<(NROWS*64)/256, 256, 0, stream>>>(X, XsB);
    vq_cvt_swz8<<<(KCENT*64)/256, 256, 0, stream>>>(CB, CBsB);
    vq_cnorm_kernel<<<KCENT/4, 256, 0, stream>>>(CB, cnorm, out + O_CNT);
    vq_gemm_kernel<<<(NROWS/256)*(KCENT/256), 1024, 0, stream>>>(XsB, CBsB, cnorm, pblk);
    vq_merge32<<<NROWS/256, 256, 0, stream>>>(pblk, pmini2);
    vq_resolve_out<<<NROWS/4, 256, 0, stream>>>(X, CB, pmini2, out);
    hipMemcpyAsync(out + O_CBV, CB, (size_t)KCENT * DDIM * sizeof(float),
                   hipMemcpyDeviceToDevice, stream);
}